// Round 13
// baseline (143.437 us; speedup 1.0000x reference)
//
#include <hip/hip_runtime.h>

#define BT     16
#define NN     10242
#define CC     64
#define KK     9
#define NBR_   7
#define OO     64
#define MT     16            // rows (nodes) per block  -> LDS 18.7KB
#define RS     584           // LDS itp row stride in bf16 (16B-aligned)
#define KT     18            // K tiles of 32
#define NTILES 641           // ceil(NN/MT)

using frag  = __attribute__((ext_vector_type(8))) short;   // 8 bf16 (4 VGPRs)
using f32x4 = __attribute__((ext_vector_type(4))) float;
using f32x2 = __attribute__((ext_vector_type(2))) float;

static __device__ __forceinline__ unsigned short f2bf(float f) {
    union { float f; unsigned u; } v; v.f = f;
    unsigned r = v.u + 0x7fffu + ((v.u >> 16) & 1u);   // RNE
    return (unsigned short)(r >> 16);
}

// packed pair via v_cvt_pk_bf16_f32 (native RNE pack — bit-identical to f2bf)
static __device__ __forceinline__ unsigned pk2(float a, float b) {
    unsigned r;
    asm("v_cvt_pk_bf16_f32 %0, %1, %2" : "=v"(r) : "v"(a), "v"(b));
    return r;
}

// q-permutation shared by producer and weight pack:
//   k in [0,8): q = (k>>2)*256 + c*4 + (k&3);  k==8: q = 512 + c
// wb[((t*4+ct)*64+lane)*8+j] = bf16(w[o][c][k]), q=t*32+(lane>>4)*8+j, o=ct*16+(lane&15)
__global__ void pack_w_kernel(const float* __restrict__ w, unsigned short* __restrict__ wb) {
    int i = blockIdx.x * blockDim.x + threadIdx.x;
    if (i >= KT * 4 * 64 * 8) return;
    int j  = i & 7;
    int l  = (i >> 3) & 63;
    int ct = (i >> 9) & 3;
    int t  = i >> 11;
    int q  = t * 32 + (l >> 4) * 8 + j;
    int o  = ct * 16 + (l & 15);
    int c, k;
    if (q < 512) { c = (q & 255) >> 2; k = (q >> 8) * 4 + (q & 3); }
    else         { c = q - 512;        k = 8; }
    wb[i] = f2bf(w[(o * CC + c) * KK + k]);
}

__global__ __launch_bounds__(256, 6) void sphere_conv_kernel(
    const float* __restrict__ x,      // (BT, N, C)
    const int*   __restrict__ index,  // (N, NBR)
    const float* __restrict__ m,      // (N, NBR, K)
    const unsigned short* __restrict__ wb,  // packed B frags (bf16 bits)
    const float* __restrict__ bias,   // (O,)
    float*       __restrict__ out)    // (BT, N, O)
{
    __shared__ unsigned short itp_s[MT * RS];   // 18688 B

    const int tid  = threadIdx.x;
    const int w    = tid >> 6;
    const int lane = tid & 63;

    // ---- XCD-ownership swizzle (bijective: 10256 % 8 == 0): XCD c owns bt
    // {2c,2c+1}, sweeps nt in slot order -> concurrent gather working set per
    // XCD = ONE 2.62MB x-slice; with nt-stores it stays in the 4MB XCD L2.
    // (R11: FETCH 141 -> 68MB)
    const int bid  = blockIdx.x;               // [0, 8*2*NTILES)
    const int xcd  = bid & 7;
    const int slot = bid >> 3;                 // [0, 2*NTILES)
    const int btl  = slot / NTILES;            // 0 or 1
    const int nt   = slot - btl * NTILES;      // [0, NTILES)
    const int bt   = xcd * 2 + btl;
    const int n0   = nt * MT;

    const frag* wbf = (const frag*)wb;
    const int ct    = w;

    // ---------------- Producer: 4 rows/wave, lane = channel ------------------
    {
        const float* xbt = x + (size_t)bt * NN * CC;

        int nu[4];
        #pragma unroll
        for (int r = 0; r < 4; ++r) {
            const int n = n0 + w * 4 + r;
            // clamp (reads stay in-bounds; junk rows never stored) + wave-uniform
            // so index/m go through scalar loads (K$/L2)
            nu[r] = __builtin_amdgcn_readfirstlane(n < NN ? n : (NN - 1));
        }

        float xv[4][NBR_];
        #pragma unroll
        for (int r = 0; r < 4; ++r) {
            const int* ip = index + nu[r] * NBR_;          // SGPR base -> s_load
            #pragma unroll
            for (int j = 0; j < NBR_; ++j)
                xv[r][j] = xbt[(size_t)ip[j] * CC + lane]; // coalesced 256B gather
        }

        #pragma unroll
        for (int r = 0; r < 4; ++r) {
            const int ns = w * 4 + r;
            const float* mp = m + nu[r] * (NBR_ * KK);     // SGPR base -> s_load

            // Packed-FP32 interp (R12): v_pk_fma_f32, 2 FMAs/instr, same per-k
            // accumulation order -> bit-identical to scalar version.
            f32x2 acc2[4];
            float acc8 = 0.f;
            #pragma unroll
            for (int p = 0; p < 4; ++p) acc2[p] = (f32x2){0.f, 0.f};
            #pragma unroll
            for (int j = 0; j < NBR_; ++j) {
                const float xvj = xv[r][j];
                const f32x2 xv2 = (f32x2){xvj, xvj};
                #pragma unroll
                for (int p = 0; p < 4; ++p) {
                    const f32x2 m2 = (f32x2){mp[j * KK + 2 * p],
                                             mp[j * KK + 2 * p + 1]};
                    acc2[p] = __builtin_elementwise_fma(xv2, m2, acc2[p]);
                }
                acc8 = fmaf(xvj, mp[j * KK + 8], acc8);
            }

            uint2 q0, q1;
            q0.x = pk2(acc2[0][0], acc2[0][1]);
            q0.y = pk2(acc2[1][0], acc2[1][1]);
            q1.x = pk2(acc2[2][0], acc2[2][1]);
            q1.y = pk2(acc2[3][0], acc2[3][1]);
            unsigned short* row = &itp_s[ns * RS];
            *(uint2*)(&row[lane * 4])       = q0;          // 8B, 2-way banks = free
            *(uint2*)(&row[256 + lane * 4]) = q1;
            row[512 + lane] = f2bf(acc8);
        }
    }

    // ---- B-prefetch: first 4 fragments issued BEFORE the barrier; their
    // latency hides entirely under the barrier wait (other waves still in
    // producer). 16 VGPRs, budget is 85 under launch_bounds(256,6).
    frag bq[4];
    #pragma unroll
    for (int t = 0; t < 4; ++t) bq[t] = wbf[(t * 4 + ct) * 64 + lane];

    __syncthreads();

    // ------------- Consumer: wave = 16 rows x 16 cols (ct = wave id) --------
    // 4-deep rotating B window: use bq[t&3], refill with fragment t+4 -> 4
    // outstanding B-loads steady-state (was ~2 under the old 64-VGPR cap).
    const int am   = lane & 15;
    const int half = lane >> 4;

    f32x4 cacc = (f32x4){0.f, 0.f, 0.f, 0.f};
    const unsigned short* arow = &itp_s[am * RS + half * 8];

    #pragma unroll
    for (int t = 0; t < KT; ++t) {                          // fully unrolled:
        const frag a = *(const frag*)(arow + t * 32);       //  bq index static
        const frag b = bq[t & 3];
        cacc = __builtin_amdgcn_mfma_f32_16x16x32_bf16(a, b, cacc, 0, 0, 0);
        if (t + 4 < KT) bq[t & 3] = wbf[((t + 4) * 4 + ct) * 64 + lane];
    }

    // ---------------- Epilogue: bias + non-temporal store --------------------
    // D layout: col = lane&15, row = (lane>>4)*4 + i. out is never re-read:
    // nt-stores keep the write stream from evicting the x-slice out of L2.
    const size_t obase = (size_t)bt * NN * OO;
    {
        const int o  = ct * 16 + am;
        const float bo = bias[o];
        #pragma unroll
        for (int i = 0; i < 4; ++i) {
            const int n = n0 + half * 4 + i;
            if (n < NN)
                __builtin_nontemporal_store(cacc[i] + bo,
                                            &out[obase + (size_t)n * OO + o]);
        }
    }
}

extern "C" void kernel_launch(void* const* d_in, const int* in_sizes, int n_in,
                              void* d_out, int out_size, void* d_ws, size_t ws_size,
                              hipStream_t stream) {
    const float* x      = (const float*)d_in[0];
    const int*   index  = (const int*)  d_in[1];
    const float* m      = (const float*)d_in[2];
    const float* conv_w = (const float*)d_in[3];
    const float* conv_b = (const float*)d_in[4];
    float* out = (float*)d_out;
    unsigned short* wb = (unsigned short*)d_ws;   // 73728 B

    {   // pack weights into MFMA B-fragment order
        const int total = KT * 4 * 64 * 8;
        pack_w_kernel<<<(total + 255) / 256, 256, 0, stream>>>(conv_w, wb);
    }
    {   // fused gather + interp + MFMA conv; 8 XCDs x 2 bt x 641 nt
        dim3 grid(8 * 2 * NTILES);                // 10256 blocks
        sphere_conv_kernel<<<grid, 256, 0, stream>>>(x, index, m, wb, conv_b, out);
    }
}